// Round 2
// baseline (439.357 us; speedup 1.0000x reference)
//
#include <hip/hip_runtime.h>

// Two-phase search, one thread per batch column.
//
// Round-1 kernel (10-deep dependent binary search, scattered tail) was
// latency-bound: each wave serialized ~10 HBM miss latencies with only
// 4 waves/CU to hide them. This version replaces the chain with two
// batches of INDEPENDENT loads:
//   Phase A: 128 coalesced samples at rows 8k+7  -> 8-row bucket (32 MB)
//   Phase B: 9-row scattered window 8c-1..8c+7   -> exact L, t0, t1 (75 MB)
//   Epilogue: 2 scattered values loads            -> interpolate (16 MB)
// Dependent-memory depth: 3 (vs 11). Traffic ~123 MB -> ~20 us BW floor.
__global__ __launch_bounds__(256) void bts_interp_kernel(
    const float* __restrict__ times,
    const float* __restrict__ values,
    const float* __restrict__ t,
    float* __restrict__ out,
    int nbatch) {
    int b = blockIdx.x * blockDim.x + threadIdx.x;
    if (b >= nbatch) return;

    float tq = t[b];

    // ---- Phase A: coarse count over sampled rows 8k+7, k = 0..127 ----
    // All 128 loads are independent and coalesced across the wave.
    const float* pA = times + 7 * nbatch + b;
    int c = 0;
    #pragma unroll 32
    for (int k = 0; k < 128; ++k) {
        float v = pA[k * 8 * nbatch];   // row 8k+7; int index < 2^26, safe
        c += (v <= tq) ? 1 : 0;
    }
    // c = #{k: times[8k+7] <= tq} in [0,128].
    // If c < 128:  L (= #times <= tq) is in [8c, 8c+7].
    // If c == 128: times[1023] <= tq  ->  L = 1024 (wrap case).

    float res;
    if (c == 128) {
        // L = 1024 -> gi = 0 -> extrapolate from the last segment (rows 1022,1023)
        int off = 1022 * nbatch + b;
        float ta = times[off], tb = times[off + nbatch];
        float va = values[off], vb = values[off + nbatch];
        res = vb + (vb - va) / (tb - ta) * (tq - tb);
    } else {
        // ---- Phase B: 9-row window, rows 8c-1 .. 8c+7 (independent loads) ----
        float tw[9];
        int base = 8 * c - 1;
        #pragma unroll
        for (int j = 0; j < 9; ++j) {
            int r = base + j;
            r = r < 0 ? 0 : r;          // c==0: row -1 clamped; unused unless L==0 (wrap)
            tw[j] = times[r * nbatch + b];
        }
        // Count rows 8c .. 8c+6 (window indices 1..7) that are <= tq.
        int cnt = 0;
        #pragma unroll
        for (int j = 1; j <= 7; ++j) cnt += (tw[j] <= tq) ? 1 : 0;
        int L = 8 * c + cnt;            // exact upper-bound count, in [8c, 8c+7]

        if (L == 0) {
            // t below all knots -> gi = 0 -> same last-segment extrapolation
            int off = 1022 * nbatch + b;
            float ta = times[off], tb = times[off + nbatch];
            float va = values[off], vb = values[off + nbatch];
            res = vb + (vb - va) / (tb - ta) * (tq - tb);
        } else {
            // Normal: iv = isl = L-1. Window index of row L-1 is cnt, of row L is cnt+1.
            float t0 = tw[cnt];         // times[L-1]
            float t1 = tw[cnt + 1];     // times[L]
            int off = (L - 1) * nbatch + b;
            float v0 = values[off];
            float v1 = values[off + nbatch];
            res = v0 + (v1 - v0) / (t1 - t0) * (tq - t0);
        }
    }
    out[b] = res;
}

extern "C" void kernel_launch(void* const* d_in, const int* in_sizes, int n_in,
                              void* d_out, int out_size, void* d_ws, size_t ws_size,
                              hipStream_t stream) {
    const float* times  = (const float*)d_in[0];
    const float* values = (const float*)d_in[1];
    const float* t      = (const float*)d_in[2];
    float* out = (float*)d_out;

    int nbatch = in_sizes[2];

    const int BLOCK = 256;
    int grid = (nbatch + BLOCK - 1) / BLOCK;
    bts_interp_kernel<<<grid, BLOCK, 0, stream>>>(times, values, t, out, nbatch);
}

// Round 3
// 424.749 us; speedup vs baseline: 1.0344x; 1.0344x over previous
//
#include <hip/hip_runtime.h>

// Stride-4 sampled search, 4 threads per column, one block = 64 columns.
//
// Cost model (per column, ntime=1024): coalesced bytes = 256MB/stride,
// scattered 128B lines = (stride-1) times-rows + 2 values-rows. Stride 4
// minimizes under a ~2x random-access penalty: 64 MB coalesced + 5 lines
// (42 MB). Round-2's stride-8 paid 11 scattered lines (92 MB) at 1 wave/SIMD.
//
// Phase A (all 256 threads): thread (x=col, y=split) scans 64 sampled rows
// 4k+3, k in [64y, 64y+64), fully coalesced (wave = one split x 64 cols).
// Captures count, last-sample<=tq, first-sample>tq. LDS-reduce across y:
//   c    = #samples <= tq            -> L in [4c, 4c+3]
//   t_lo = times[4c-1] (if c>0),  t_hi = times[4c+3] (if c<256)
// Phase B (wave y==0 only): 3 scattered times rows 4c..4c+2 give exact
// L = 4c + c2 and both interpolation knots t0=times[L-1], t1=times[L]
// without further loads; then 2 scattered values rows, interpolate.
// Wrap (L==0 or L==ntime, ~1e-3 of columns): extrapolate from last segment.
__global__ __launch_bounds__(256) void bts_interp_kernel(
    const float* __restrict__ times,
    const float* __restrict__ values,
    const float* __restrict__ t,
    float* __restrict__ out,
    int ntime, int nbatch) {
    const int x = threadIdx.x;              // column within block, 0..63
    const int y = threadIdx.y;              // split, 0..3
    const int b = blockIdx.x * 64 + x;

    const int K = ntime >> 4;               // samples per thread (64)
    const float tq = t[b];

    // ---- Phase A: coalesced scan of sampled rows 4*(y*K+k)+3 ----
    const float* p = times + (size_t)(4 * y * K + 3) * nbatch + b;
    int cnt = 0;
    float tlo = -1.0f;                      // last sample <= tq (ascending)
    float thi = 2.0f;                       // first sample  > tq
    #pragma unroll 16
    for (int k = 0; k < K; ++k) {
        float v = p[(size_t)k * 4 * nbatch];
        bool le = (v <= tq);
        cnt += le ? 1 : 0;
        tlo = le ? v : tlo;
        thi = fminf(thi, le ? 2.0f : v);
    }

    __shared__ int   s_cnt[4][64];
    __shared__ float s_tlo[4][64];
    __shared__ float s_thi[4][64];
    s_cnt[y][x] = cnt;
    s_tlo[y][x] = tlo;
    s_thi[y][x] = thi;
    __syncthreads();

    if (y != 0) return;

    // ---- Reduce across the 4 splits ----
    int c = s_cnt[0][x] + s_cnt[1][x] + s_cnt[2][x] + s_cnt[3][x];
    float t_lo = fmaxf(fmaxf(s_tlo[0][x], s_tlo[1][x]),
                       fmaxf(s_tlo[2][x], s_tlo[3][x]));
    float t_hi = fminf(fminf(s_thi[0][x], s_thi[1][x]),
                       fminf(s_thi[2][x], s_thi[3][x]));

    // ---- Phase B: refine within the 4-row bucket ----
    const int nsamp = ntime >> 2;
    int L;
    float t0 = 0.0f, t1 = 1.0f;
    if (c == nsamp) {
        L = ntime;                           // times[ntime-1] <= tq
    } else {
        size_t w = (size_t)(4 * c) * nbatch + b;
        float w0 = times[w];
        float w1 = times[w + nbatch];
        float w2 = times[w + 2 * (size_t)nbatch];
        int c2 = (w0 <= tq ? 1 : 0) + (w1 <= tq ? 1 : 0) + (w2 <= tq ? 1 : 0);
        L = 4 * c + c2;
        t0 = (c2 == 0) ? t_lo : (c2 == 1 ? w0 : (c2 == 2 ? w1 : w2));
        t1 = (c2 == 3) ? t_hi : (c2 == 0 ? w0 : (c2 == 1 ? w1 : w2));
    }

    float res;
    if (L == 0 || L == ntime) {
        // gi == 0: torch negative-wrap -> extrapolate from last segment
        size_t off = (size_t)(ntime - 2) * nbatch + b;
        float ta = times[off], tb = times[off + nbatch];
        float va = values[off], vb = values[off + nbatch];
        res = vb + (vb - va) / (tb - ta) * (tq - tb);
    } else {
        size_t off = (size_t)(L - 1) * nbatch + b;
        float v0 = values[off], v1 = values[off + nbatch];
        res = v0 + (v1 - v0) / (t1 - t0) * (tq - t0);
    }
    out[b] = res;
}

extern "C" void kernel_launch(void* const* d_in, const int* in_sizes, int n_in,
                              void* d_out, int out_size, void* d_ws, size_t ws_size,
                              hipStream_t stream) {
    const float* times  = (const float*)d_in[0];
    const float* values = (const float*)d_in[1];
    const float* t      = (const float*)d_in[2];
    float* out = (float*)d_out;

    int nbatch = in_sizes[2];
    int ntime  = in_sizes[0] / nbatch;      // 1024

    dim3 block(64, 4);
    int grid = nbatch / 64;                 // 65536/64 = 1024 blocks
    bts_interp_kernel<<<grid, block, 0, stream>>>(times, values, t, out, ntime, nbatch);
}